// Round 4
// baseline (362.523 us; speedup 1.0000x reference)
//
#include <hip/hip_runtime.h>
#include <math.h>

#define D_DIM 1024
#define H_DIM 4096
#define R_DIM 64
#define S_SP  4
#define NTOK  8192
#define CHUNK 1024   // H/S

// ---------------- K0: transpose W2 (D,H) -> W2T (H,D) ----------------
__global__ __launch_bounds__(256) void k_transpose(const float* __restrict__ W2,
                                                   float* __restrict__ W2T) {
  __shared__ float tile[64][65];
  const int hb = blockIdx.x * 64, db = blockIdx.y * 64;
  const int tx = threadIdx.x & 63, ty = threadIdx.x >> 6;
#pragma unroll
  for (int r = 0; r < 16; ++r) {
    const int d = ty * 16 + r;
    tile[tx][d] = W2[(size_t)(db + d) * H_DIM + hb + tx];
  }
  __syncthreads();
#pragma unroll
  for (int r = 0; r < 16; ++r) {
    const int h = ty * 16 + r;
    W2T[(size_t)(hb + h) * D_DIM + db + tx] = tile[h][tx];
  }
}

// ---------------- K1: ch = relu(x @ Wc1^T + bc1)  (8192x64, K=1024) ----
// x reads are wave-uniform (g = tid>>6 constant per wave) -> SMEM s_load;
// Wc1 row chunks are per-lane VMEM. No LDS at all.
#define K1_TOK 16
__global__ __launch_bounds__(256, 4) void k_ctrl(const float* __restrict__ x,
                                                 const float* __restrict__ Wc1,
                                                 const float* __restrict__ bc1,
                                                 float* __restrict__ ch) {
  const int tid = threadIdx.x;
  const int tok0 = blockIdx.x * K1_TOK;
  const int r = tid & 63;   // output column r (R=64)
  const int g = tid >> 6;   // token group 0..3 (4 tokens each, wave-uniform)
  float acc[4] = {0.f, 0.f, 0.f, 0.f};
#pragma unroll 1
  for (int c = 0; c < 64; ++c) {      // 16-float chunks of the K dim
    const int k0 = c * 16;
    const float4 w0 = *(const float4*)(Wc1 + (size_t)r * D_DIM + k0 + 0);
    const float4 w1 = *(const float4*)(Wc1 + (size_t)r * D_DIM + k0 + 4);
    const float4 w2 = *(const float4*)(Wc1 + (size_t)r * D_DIM + k0 + 8);
    const float4 w3 = *(const float4*)(Wc1 + (size_t)r * D_DIM + k0 + 12);
#pragma unroll
    for (int t = 0; t < 4; ++t) {
      const float* cp = x + (size_t)(tok0 + g * 4 + t) * D_DIM + k0;  // wave-uniform
      const float4 c0 = *(const float4*)(cp + 0);
      const float4 c1 = *(const float4*)(cp + 4);
      const float4 c2 = *(const float4*)(cp + 8);
      const float4 c3 = *(const float4*)(cp + 12);
      float a = acc[t];
      a = fmaf(c0.x, w0.x, a); a = fmaf(c0.y, w0.y, a);
      a = fmaf(c0.z, w0.z, a); a = fmaf(c0.w, w0.w, a);
      a = fmaf(c1.x, w1.x, a); a = fmaf(c1.y, w1.y, a);
      a = fmaf(c1.z, w1.z, a); a = fmaf(c1.w, w1.w, a);
      a = fmaf(c2.x, w2.x, a); a = fmaf(c2.y, w2.y, a);
      a = fmaf(c2.z, w2.z, a); a = fmaf(c2.w, w2.w, a);
      a = fmaf(c3.x, w3.x, a); a = fmaf(c3.y, w3.y, a);
      a = fmaf(c3.z, w3.z, a); a = fmaf(c3.w, w3.w, a);
      acc[t] = a;
    }
  }
#pragma unroll
  for (int t = 0; t < 4; ++t) {
    const float v = acc[t] + bc1[r];
    ch[(size_t)(tok0 + g * 4 + t) * R_DIM + r] = v > 0.f ? v : 0.f;
  }
}

// ------- K2: logits = ch @ Wc2^T + bc2 (+gumbel), per-chunk argmax ------
// ch reads are block-uniform -> SMEM s_load (no LDS staging). Wc2 row is
// per-lane VMEM. LDS only for the tiny cross-wave argmax combine.
#define K2_TOK 16
__global__ __launch_bounds__(256, 4) void k_gate(const float* __restrict__ ch,
                                                 const float* __restrict__ Wc2,
                                                 const float* __restrict__ bc2,
                                                 const float* __restrict__ gumbel,
                                                 int* __restrict__ idx) {
  __shared__ float redv[4][K2_TOK];
  __shared__ int   redi[4][K2_TOK];
  const int tid = threadIdx.x;
  const int tok0 = blockIdx.x * K2_TOK;
  const int s = blockIdx.y;
  float bv[K2_TOK];
  int   bi[K2_TOK];
#pragma unroll
  for (int t = 0; t < K2_TOK; ++t) { bv[t] = -INFINITY; bi[t] = 0; }
#pragma unroll 1
  for (int hi = 0; hi < 4; ++hi) {
    const int hloc = hi * 256 + tid;              // h within chunk, 0..1023
    const float* wrow = Wc2 + (size_t)(s * CHUNK + hloc) * R_DIM;
    float acc[K2_TOK];
#pragma unroll
    for (int t = 0; t < K2_TOK; ++t) acc[t] = 0.f;
#pragma unroll 1
    for (int kk = 0; kk < 4; ++kk) {
      const float4 w0 = *(const float4*)(wrow + kk * 16 + 0);
      const float4 w1 = *(const float4*)(wrow + kk * 16 + 4);
      const float4 w2 = *(const float4*)(wrow + kk * 16 + 8);
      const float4 w3 = *(const float4*)(wrow + kk * 16 + 12);
#pragma unroll
      for (int t = 0; t < K2_TOK; ++t) {
        const float* cp = ch + (size_t)(tok0 + t) * R_DIM + kk * 16;  // block-uniform
        const float4 c0 = *(const float4*)(cp + 0);
        const float4 c1 = *(const float4*)(cp + 4);
        const float4 c2 = *(const float4*)(cp + 8);
        const float4 c3 = *(const float4*)(cp + 12);
        float a = acc[t];
        a = fmaf(c0.x, w0.x, a); a = fmaf(c0.y, w0.y, a);
        a = fmaf(c0.z, w0.z, a); a = fmaf(c0.w, w0.w, a);
        a = fmaf(c1.x, w1.x, a); a = fmaf(c1.y, w1.y, a);
        a = fmaf(c1.z, w1.z, a); a = fmaf(c1.w, w1.w, a);
        a = fmaf(c2.x, w2.x, a); a = fmaf(c2.y, w2.y, a);
        a = fmaf(c2.z, w2.z, a); a = fmaf(c2.w, w2.w, a);
        a = fmaf(c3.x, w3.x, a); a = fmaf(c3.y, w3.y, a);
        a = fmaf(c3.z, w3.z, a); a = fmaf(c3.w, w3.w, a);
        acc[t] = a;
      }
    }
    const float bias = bc2[s * CHUNK + hloc];
    const float* gp = gumbel + ((size_t)tok0 * 4 + s) * CHUNK + hloc;
#pragma unroll
    for (int t = 0; t < K2_TOK; ++t) {
      const float val = acc[t] + bias + gp[(size_t)t * 4 * CHUNK];
      if (val > bv[t] || (val == bv[t] && hloc < bi[t])) { bv[t] = val; bi[t] = hloc; }
    }
  }
  // argmax reduce: wave shuffle, then cross-wave via LDS
#pragma unroll
  for (int t = 0; t < K2_TOK; ++t) {
    float v = bv[t];
    int ii = bi[t];
#pragma unroll
    for (int o = 32; o > 0; o >>= 1) {
      const float ov = __shfl_down(v, o);
      const int   oi = __shfl_down(ii, o);
      if (ov > v || (ov == v && oi < ii)) { v = ov; ii = oi; }
    }
    if ((tid & 63) == 0) { redv[tid >> 6][t] = v; redi[tid >> 6][t] = ii; }
  }
  __syncthreads();
  if (tid < K2_TOK) {
    float v = redv[0][tid];
    int ii = redi[0][tid];
#pragma unroll
    for (int wv = 1; wv < 4; ++wv) {
      const float ov = redv[wv][tid];
      const int   oi = redi[wv][tid];
      if (ov > v || (ov == v && oi < ii)) { v = ov; ii = oi; }
    }
    idx[(size_t)(tok0 + tid) * S_SP + s] = s * CHUNK + ii;
  }
}

// ------- K3: wave-per-token sparse FFN (4 tokens/block, no syncthreads) ---
__global__ __launch_bounds__(256) void k_ffn(const float* __restrict__ x,
                                             const float* __restrict__ W1,
                                             const float* __restrict__ b1,
                                             const float* __restrict__ W2T,
                                             const float* __restrict__ b2,
                                             const int* __restrict__ idx,
                                             float* __restrict__ out) {
  const int tid  = threadIdx.x;
  const int lane = tid & 63;
  const int wv   = tid >> 6;
  const int token = blockIdx.x * 4 + wv;
  const int4 h4 = *(const int4*)(idx + (size_t)token * S_SP);
  const int h[4] = {h4.x, h4.y, h4.z, h4.w};
  const int d0 = lane * 16;
  const float* xp = x + (size_t)token * D_DIM + d0;
  const float4 x0 = *(const float4*)(xp + 0);
  const float4 x1 = *(const float4*)(xp + 4);
  const float4 x2 = *(const float4*)(xp + 8);
  const float4 x3 = *(const float4*)(xp + 12);
  float p[4];
#pragma unroll
  for (int s2 = 0; s2 < 4; ++s2) {
    const float* wr = W1 + (size_t)h[s2] * D_DIM + d0;
    const float4 a0 = *(const float4*)(wr + 0);
    const float4 a1 = *(const float4*)(wr + 4);
    const float4 a2 = *(const float4*)(wr + 8);
    const float4 a3 = *(const float4*)(wr + 12);
    float v = 0.f;
    v = fmaf(x0.x, a0.x, v); v = fmaf(x0.y, a0.y, v);
    v = fmaf(x0.z, a0.z, v); v = fmaf(x0.w, a0.w, v);
    v = fmaf(x1.x, a1.x, v); v = fmaf(x1.y, a1.y, v);
    v = fmaf(x1.z, a1.z, v); v = fmaf(x1.w, a1.w, v);
    v = fmaf(x2.x, a2.x, v); v = fmaf(x2.y, a2.y, v);
    v = fmaf(x2.z, a2.z, v); v = fmaf(x2.w, a2.w, v);
    v = fmaf(x3.x, a3.x, v); v = fmaf(x3.y, a3.y, v);
    v = fmaf(x3.z, a3.z, v); v = fmaf(x3.w, a3.w, v);
    p[s2] = v;
  }
  // butterfly reduce across the wave: every lane ends with the full dot
#pragma unroll
  for (int s2 = 0; s2 < 4; ++s2) {
#pragma unroll
    for (int o = 1; o < 64; o <<= 1) p[s2] += __shfl_xor(p[s2], o);
  }
  float hvv[4];
#pragma unroll
  for (int s2 = 0; s2 < 4; ++s2) {
    const float v = p[s2] + b1[h[s2]];
    hvv[s2] = v > 0.f ? v : 0.f;
  }
  float4 o0 = *(const float4*)(b2 + d0 + 0);
  float4 o1 = *(const float4*)(b2 + d0 + 4);
  float4 o2 = *(const float4*)(b2 + d0 + 8);
  float4 o3 = *(const float4*)(b2 + d0 + 12);
#pragma unroll
  for (int s2 = 0; s2 < 4; ++s2) {
    const float* wr = W2T + (size_t)h[s2] * D_DIM + d0;
    const float4 a0 = *(const float4*)(wr + 0);
    const float4 a1 = *(const float4*)(wr + 4);
    const float4 a2 = *(const float4*)(wr + 8);
    const float4 a3 = *(const float4*)(wr + 12);
    const float g = hvv[s2];
    o0.x = fmaf(g, a0.x, o0.x); o0.y = fmaf(g, a0.y, o0.y);
    o0.z = fmaf(g, a0.z, o0.z); o0.w = fmaf(g, a0.w, o0.w);
    o1.x = fmaf(g, a1.x, o1.x); o1.y = fmaf(g, a1.y, o1.y);
    o1.z = fmaf(g, a1.z, o1.z); o1.w = fmaf(g, a1.w, o1.w);
    o2.x = fmaf(g, a2.x, o2.x); o2.y = fmaf(g, a2.y, o2.y);
    o2.z = fmaf(g, a2.z, o2.z); o2.w = fmaf(g, a2.w, o2.w);
    o3.x = fmaf(g, a3.x, o3.x); o3.y = fmaf(g, a3.y, o3.y);
    o3.z = fmaf(g, a3.z, o3.z); o3.w = fmaf(g, a3.w, o3.w);
  }
  float* op = out + (size_t)token * D_DIM + d0;
  *(float4*)(op + 0)  = o0;
  *(float4*)(op + 4)  = o1;
  *(float4*)(op + 8)  = o2;
  *(float4*)(op + 12) = o3;
}

extern "C" void kernel_launch(void* const* d_in, const int* in_sizes, int n_in,
                              void* d_out, int out_size, void* d_ws, size_t ws_size,
                              hipStream_t stream) {
  const float* x      = (const float*)d_in[0];
  const float* W1     = (const float*)d_in[1];
  const float* b1     = (const float*)d_in[2];
  const float* W2     = (const float*)d_in[3];
  const float* b2     = (const float*)d_in[4];
  const float* Wc1    = (const float*)d_in[5];
  const float* bc1    = (const float*)d_in[6];
  const float* Wc2    = (const float*)d_in[7];
  const float* bc2    = (const float*)d_in[8];
  const float* gumbel = (const float*)d_in[9];
  float* out = (float*)d_out;

  char* ws = (char*)d_ws;
  float* W2T = (float*)ws;                                           // 16.78 MB
  float* ch  = (float*)(ws + (size_t)H_DIM * D_DIM * 4);             //  2.10 MB
  int*   idx = (int*)(ws + (size_t)H_DIM * D_DIM * 4
                         + (size_t)NTOK * R_DIM * 4);                //  0.13 MB

  hipLaunchKernelGGL(k_transpose, dim3(H_DIM / 64, D_DIM / 64), dim3(256), 0, stream,
                     W2, W2T);
  hipLaunchKernelGGL(k_ctrl, dim3(NTOK / K1_TOK), dim3(256), 0, stream,
                     x, Wc1, bc1, ch);
  hipLaunchKernelGGL(k_gate, dim3(NTOK / K2_TOK, S_SP), dim3(256), 0, stream,
                     ch, Wc2, bc2, gumbel, idx);
  hipLaunchKernelGGL(k_ffn, dim3(NTOK / 4), dim3(256), 0, stream,
                     x, W1, b1, W2T, b2, idx, out);
}